// Round 1
// baseline (11824.672 us; speedup 1.0000x reference)
//
#include <hip/hip_runtime.h>
#include <hip/hip_bf16.h>

typedef __attribute__((ext_vector_type(8))) short   short8;
typedef __attribute__((ext_vector_type(4))) short   short4_;
typedef __attribute__((ext_vector_type(4))) float   float4_;

// ---------------- workspace layout (bytes) ----------------
#define WPACK_OFF   0
#define WPACK_BYTES 786432              // 1024 rows x 384 k x 2B, A-frag packed
#define HBUF_OFF    786432
#define HBUF_BYTES  262144              // 2 x 16grp x 16b x 256k x bf16
#define BIAS_OFF    (HBUF_OFF + HBUF_BYTES)   // 1048576
#define BIAS_BYTES  4096
#define FLAGS_OFF   (BIAS_OFF + BIAS_BYTES)   // 1052672
#define FLAGS_BYTES 256

__device__ __forceinline__ unsigned short f2bf(float f) {
  unsigned int u = __float_as_uint(f);
  u += 0x7fffu + ((u >> 16) & 1u);       // round-to-nearest-even
  return (unsigned short)(u >> 16);
}

// Pack W = [W_hh | W_ih] into MFMA A-fragment order, bf16.
// idx = (((s*4+w)*4+mt)*12+kt)*64+lane ; each thread writes one 16B frag.
__global__ void pack_w(const float* __restrict__ w_ih,
                       const float* __restrict__ w_hh,
                       unsigned short* __restrict__ wpack) {
  int idx = blockIdx.x * blockDim.x + threadIdx.x;
  if (idx >= 49152) return;
  int lane = idx & 63;
  int r1 = idx >> 6;
  int kt = r1 % 12;
  int r2 = r1 / 12;
  int mt = r2 & 3;          // gate (i,f,g,o)
  int r3 = r2 >> 2;
  int w  = r3 & 3;          // wave in block
  int s  = r3 >> 2;         // gate-slice (which block of the group)
  int row = mt * 256 + s * 64 + w * 16 + (lane & 15);
  int q = lane >> 4;
  unsigned short tmp[8];
#pragma unroll
  for (int j = 0; j < 8; ++j) {
    int kk = kt * 32 + q * 8 + j;        // 0..383
    float v = (kt < 8) ? w_hh[row * 256 + kk]
                       : w_ih[row * 128 + (kk - 256)];
    tmp[j] = f2bf(v);
  }
  short8 o;
#pragma unroll
  for (int j = 0; j < 8; ++j) o[j] = (short)tmp[j];
  *(short8*)(wpack + (size_t)idx * 8) = o;
}

// Seed hbuf[0] with bf16(h0) in [grp][b][k] layout, and bias_sum = b_ih+b_hh.
__global__ void init_hb(const float* __restrict__ h0,
                        const float* __restrict__ b_ih,
                        const float* __restrict__ b_hh,
                        unsigned short* __restrict__ hbuf,
                        float* __restrict__ bias) {
  int idx = blockIdx.x * blockDim.x + threadIdx.x;
  if (idx < 65536) {
    hbuf[idx] = f2bf(h0[idx]);           // b*256+k == (grp*16+bl)*256+k
  } else if (idx < 66560) {
    int j = idx - 65536;
    bias[j] = b_ih[j] + b_hh[j];
  }
}

__device__ __forceinline__ float sigm_(float v) {
  return 1.f / (1.f + __expf(-v));
}
__device__ __forceinline__ float tanh_(float v) {
  return 1.f - 2.f / (__expf(2.f * v) + 1.f);   // robust at +-inf
}

__global__ __launch_bounds__(256, 1) void lstm_main(
    const float* __restrict__ x, const float* __restrict__ c0,
    const unsigned short* __restrict__ wpack, const float* __restrict__ bias,
    unsigned short* hbuf, int* flags, float* __restrict__ out) {

  const int tid  = threadIdx.x;
  const int w    = tid >> 6;       // wave 0..3
  const int lane = tid & 63;
  const int q    = lane >> 4;
  const int bl   = lane & 15;

  // XCD-affinity swizzle: the 4 blocks of a group share blockIdx%8.
  int id  = blockIdx.x;
  int xcd = id & 7;
  int j3  = id >> 3;
  int s   = j3 & 3;                         // gate-slice 0..3
  int grp = (j3 >> 2) * 8 + xcd;            // batch group 0..15

  const int n0    = s * 64 + w * 16;        // wave's first h-element
  const int bglob = grp * 16 + bl;

  // ---- W fragments resident in VGPRs: 4 gates x 12 ktiles ----
  short8 wf[48];
  {
    const unsigned short* base =
        wpack + ((size_t)((s * 4 + w) * 48) * 64 + lane) * 8;
#pragma unroll
    for (int f = 0; f < 48; ++f)
      wf[f] = *(const short8*)(base + (size_t)f * 64 * 8);
  }

  // bias (acc init), c state
  float4_ bia[4];
#pragma unroll
  for (int g = 0; g < 4; ++g)
    bia[g] = *(const float4_*)(bias + g * 256 + n0 + q * 4);
  float4_ c = *(const float4_*)(c0 + (size_t)bglob * 256 + n0 + q * 4);

  // own-slice LDS double buffer: [parity][b][64k + pad] (row 144B, 9 odd -> no conflicts)
  __shared__ unsigned short hl[2][16][72];
  {
    const unsigned short* src = hbuf + (size_t)bglob * 256 + n0 + q * 4;
    *(short4_*)&hl[0][bl][w * 16 + q * 4] = *(const short4_*)src;
  }
  __syncthreads();

  // x prefetch for t=0 (ktiles 8..11 of K)
  float4_ xr[8];
  {
    const float* xb = x + (size_t)bglob * 131072 + q * 8;
#pragma unroll
    for (int kx = 0; kx < 4; ++kx) {
      xr[kx * 2]     = *(const float4_*)(xb + kx * 32);
      xr[kx * 2 + 1] = *(const float4_*)(xb + kx * 32 + 4);
    }
  }

  int ps[3];
  {
    int cc = 0;
#pragma unroll
    for (int ss = 0; ss < 4; ++ss) if (ss != s) ps[cc++] = ss;
  }

  float4_ hval;

  for (int t = 0; t < 1024; ++t) {
    const int p = t & 1;

    // convert prefetched x -> bf16 frags
    short8 xf[4];
#pragma unroll
    for (int kx = 0; kx < 4; ++kx) {
      short8 v;
#pragma unroll
      for (int e = 0; e < 4; ++e) {
        v[e]     = (short)f2bf(xr[kx * 2][e]);
        v[e + 4] = (short)f2bf(xr[kx * 2 + 1][e]);
      }
      xf[kx] = v;
    }
    // prefetch next step's x (full step of latency cover)
    {
      int tn = (t < 1023) ? (t + 1) : 1023;
      const float* xb = x + (size_t)bglob * 131072 + (size_t)tn * 128 + q * 8;
#pragma unroll
      for (int kx = 0; kx < 4; ++kx) {
        xr[kx * 2]     = *(const float4_*)(xb + kx * 32);
        xr[kx * 2 + 1] = *(const float4_*)(xb + kx * 32 + 4);
      }
    }

    // ---- wait for peers' h_t ----
    {
      for (;;) {
        int f0 = __hip_atomic_load(&flags[grp * 4 + ps[0]], __ATOMIC_RELAXED,
                                   __HIP_MEMORY_SCOPE_AGENT);
        int f1 = __hip_atomic_load(&flags[grp * 4 + ps[1]], __ATOMIC_RELAXED,
                                   __HIP_MEMORY_SCOPE_AGENT);
        int f2 = __hip_atomic_load(&flags[grp * 4 + ps[2]], __ATOMIC_RELAXED,
                                   __HIP_MEMORY_SCOPE_AGENT);
        if (f0 >= t && f1 >= t && f2 >= t) break;
        __builtin_amdgcn_s_sleep(1);
      }
      __builtin_amdgcn_fence(__ATOMIC_ACQUIRE, "agent");
    }

    // issue peer h loads early (latency hidden behind own+x MFMAs)
    unsigned long long pl[12];
#pragma unroll
    for (int pi = 0; pi < 3; ++pi) {
      int ss = ps[pi];
      unsigned long long* hb = (unsigned long long*)(hbuf +
          ((size_t)((p * 16 + grp) * 16 + bl) * 256 + ss * 64 + q * 8));
      pl[pi * 4 + 0] = __hip_atomic_load(hb + 0, __ATOMIC_RELAXED, __HIP_MEMORY_SCOPE_AGENT);
      pl[pi * 4 + 1] = __hip_atomic_load(hb + 1, __ATOMIC_RELAXED, __HIP_MEMORY_SCOPE_AGENT);
      pl[pi * 4 + 2] = __hip_atomic_load(hb + 8, __ATOMIC_RELAXED, __HIP_MEMORY_SCOPE_AGENT);
      pl[pi * 4 + 3] = __hip_atomic_load(hb + 9, __ATOMIC_RELAXED, __HIP_MEMORY_SCOPE_AGENT);
    }

    float4_ acc[4];
#pragma unroll
    for (int g = 0; g < 4; ++g) acc[g] = bia[g];

    // own slice from LDS: global ktiles 2s, 2s+1
    {
      short8 bo0 = *(const short8*)&hl[p][bl][q * 8];
      short8 bo1 = *(const short8*)&hl[p][bl][32 + q * 8];
#pragma unroll
      for (int g = 0; g < 4; ++g)
        acc[g] = __builtin_amdgcn_mfma_f32_16x16x32_bf16(wf[g * 12 + 2 * s], bo0, acc[g], 0, 0, 0);
#pragma unroll
      for (int g = 0; g < 4; ++g)
        acc[g] = __builtin_amdgcn_mfma_f32_16x16x32_bf16(wf[g * 12 + 2 * s + 1], bo1, acc[g], 0, 0, 0);
    }

    // x contribution: ktiles 8..11
#pragma unroll
    for (int kx = 0; kx < 4; ++kx)
#pragma unroll
      for (int g = 0; g < 4; ++g)
        acc[g] = __builtin_amdgcn_mfma_f32_16x16x32_bf16(wf[g * 12 + 8 + kx], xf[kx], acc[g], 0, 0, 0);

    // peers' h slices
#pragma unroll
    for (int pi = 0; pi < 3; ++pi) {
      int ss = ps[pi];
#pragma unroll
      for (int kt = 0; kt < 2; ++kt) {
        union { unsigned long long u[2]; short8 v; } uu;
        uu.u[0] = pl[pi * 4 + kt * 2 + 0];
        uu.u[1] = pl[pi * 4 + kt * 2 + 1];
#pragma unroll
        for (int g = 0; g < 4; ++g)
          acc[g] = __builtin_amdgcn_mfma_f32_16x16x32_bf16(wf[g * 12 + 2 * ss + kt], uu.v, acc[g], 0, 0, 0);
      }
    }

    // ---- gates / state update (fp32) ----
    unsigned short hp[4];
#pragma unroll
    for (int r = 0; r < 4; ++r) {
      float iv = sigm_(acc[0][r]);
      float fv = sigm_(acc[1][r]);
      float gv = tanh_(acc[2][r]);
      float ov = sigm_(acc[3][r]);
      float cv = fv * c[r] + iv * gv;
      c[r] = cv;
      float hv = ov * tanh_(cv);
      hval[r] = hv;
      hp[r] = f2bf(hv);
    }

    // write h_{t+1}: LDS (own slice) + global (peers), agent-scope store
    {
      short4_ sv;
#pragma unroll
      for (int r = 0; r < 4; ++r) sv[r] = (short)hp[r];
      *(short4_*)&hl[1 - p][bl][w * 16 + q * 4] = sv;
      unsigned long long hu = (unsigned long long)hp[0]
                            | ((unsigned long long)hp[1] << 16)
                            | ((unsigned long long)hp[2] << 32)
                            | ((unsigned long long)hp[3] << 48);
      unsigned long long* dst = (unsigned long long*)(hbuf +
          ((size_t)(((1 - p) * 16 + grp) * 16 + bl) * 256 + n0 + q * 4));
      __hip_atomic_store(dst, hu, __ATOMIC_RELAXED, __HIP_MEMORY_SCOPE_AGENT);
    }

    __syncthreads();   // drains vmcnt for all waves before flag
    if (tid == 0)
      __hip_atomic_store(&flags[grp * 4 + s], t + 1, __ATOMIC_RELEASE,
                         __HIP_MEMORY_SCOPE_AGENT);
  }

  // final h (fp32) -> d_out [1,B,H]
  *(float4_*)(out + (size_t)bglob * 256 + n0 + q * 4) = hval;
}

extern "C" void kernel_launch(void* const* d_in, const int* in_sizes, int n_in,
                              void* d_out, int out_size, void* d_ws, size_t ws_size,
                              hipStream_t stream) {
  (void)in_sizes; (void)n_in; (void)out_size; (void)ws_size;
  const float* x    = (const float*)d_in[0];
  const float* h0   = (const float*)d_in[1];
  const float* c0   = (const float*)d_in[2];
  const float* w_ih = (const float*)d_in[3];
  const float* w_hh = (const float*)d_in[4];
  const float* b_ih = (const float*)d_in[5];
  const float* b_hh = (const float*)d_in[6];

  char* ws = (char*)d_ws;
  unsigned short* wpack = (unsigned short*)(ws + WPACK_OFF);
  unsigned short* hbuf  = (unsigned short*)(ws + HBUF_OFF);
  float*          bias  = (float*)(ws + BIAS_OFF);
  int*            flags = (int*)(ws + FLAGS_OFF);

  hipMemsetAsync(flags, 0, FLAGS_BYTES, stream);
  pack_w<<<192, 256, 0, stream>>>(w_ih, w_hh, wpack);
  init_hb<<<260, 256, 0, stream>>>(h0, b_ih, b_hh, hbuf, bias);
  lstm_main<<<64, 256, 0, stream>>>(x, c0, wpack, bias, hbuf, flags,
                                    (float*)d_out);
}

// Round 2
// 11437.050 us; speedup vs baseline: 1.0339x; 1.0339x over previous
//
#include <hip/hip_runtime.h>
#include <hip/hip_bf16.h>

typedef __attribute__((ext_vector_type(8))) short   short8;
typedef __attribute__((ext_vector_type(4))) float   float4_;

// ---------------- workspace layout (bytes) ----------------
#define WPACK_OFF   0
#define WPACK_BYTES 786432              // 1024 rows x 384 k x 2B, A-frag packed
#define HBUF_OFF    786432
#define HBUF_BYTES  262144              // 2 x 16grp x 16b x 256k x bf16
#define BIAS_OFF    (HBUF_OFF + HBUF_BYTES)   // 1048576
#define BIAS_BYTES  4096
#define FLAGS_OFF   (BIAS_OFF + BIAS_BYTES)   // 1052672
#define FLAGS_BYTES 256

__device__ __forceinline__ unsigned short f2bf(float f) {
  unsigned int u = __float_as_uint(f);
  u += 0x7fffu + ((u >> 16) & 1u);       // round-to-nearest-even
  return (unsigned short)(u >> 16);
}

// Pack W = [W_hh | W_ih] into MFMA A-fragment order, bf16.
// idx = (((s*4+w)*4+mt)*12+kt)*64+lane ; each thread writes one 16B frag.
__global__ void pack_w(const float* __restrict__ w_ih,
                       const float* __restrict__ w_hh,
                       unsigned short* __restrict__ wpack) {
  int idx = blockIdx.x * blockDim.x + threadIdx.x;
  if (idx >= 49152) return;
  int lane = idx & 63;
  int r1 = idx >> 6;
  int kt = r1 % 12;
  int r2 = r1 / 12;
  int mt = r2 & 3;          // gate (i,f,g,o)
  int r3 = r2 >> 2;
  int w  = r3 & 3;          // wave in block
  int s  = r3 >> 2;         // gate-slice (which block of the group)
  int row = mt * 256 + s * 64 + w * 16 + (lane & 15);
  int q = lane >> 4;
  unsigned short tmp[8];
#pragma unroll
  for (int j = 0; j < 8; ++j) {
    int kk = kt * 32 + q * 8 + j;        // 0..383
    float v = (kt < 8) ? w_hh[row * 256 + kk]
                       : w_ih[row * 128 + (kk - 256)];
    tmp[j] = f2bf(v);
  }
  short8 o;
#pragma unroll
  for (int j = 0; j < 8; ++j) o[j] = (short)tmp[j];
  *(short8*)(wpack + (size_t)idx * 8) = o;
}

// Seed hbuf[0] with bf16(h0) in [grp][b][k] layout, and bias_sum = b_ih+b_hh.
__global__ void init_hb(const float* __restrict__ h0,
                        const float* __restrict__ b_ih,
                        const float* __restrict__ b_hh,
                        unsigned short* __restrict__ hbuf,
                        float* __restrict__ bias) {
  int idx = blockIdx.x * blockDim.x + threadIdx.x;
  if (idx < 65536) {
    hbuf[idx] = f2bf(h0[idx]);           // b*256+k == (grp*16+bl)*256+k
  } else if (idx < 66560) {
    int j = idx - 65536;
    bias[j] = b_ih[j] + b_hh[j];
  }
}

__device__ __forceinline__ float sigm_(float v) {
  return 1.f / (1.f + __expf(-v));
}
__device__ __forceinline__ float tanh_(float v) {
  return 1.f - 2.f / (__expf(2.f * v) + 1.f);   // robust at +-inf
}

__global__ __launch_bounds__(256, 1) void lstm_main(
    const float* __restrict__ x, const float* __restrict__ c0,
    const unsigned short* __restrict__ wpack, const float* __restrict__ bias,
    unsigned short* hbuf, int* flags, float* __restrict__ out) {

  const int tid  = threadIdx.x;
  const int w    = tid >> 6;       // wave 0..3
  const int lane = tid & 63;
  const int q    = lane >> 4;
  const int bl   = lane & 15;

  // XCD-affinity swizzle: the 4 blocks of a group share blockIdx%8.
  int id  = blockIdx.x;
  int xcd = id & 7;
  int j3  = id >> 3;
  int s   = j3 & 3;                         // gate-slice 0..3
  int grp = (j3 >> 2) * 8 + xcd;            // batch group 0..15

  const int n0    = s * 64 + w * 16;        // wave's first h-element
  const int bglob = grp * 16 + bl;

  // ---- W fragments resident in VGPRs: 4 gates x 12 ktiles (ALL static idx) ----
  short8 wf[48];
  {
    const unsigned short* base =
        wpack + ((size_t)((s * 4 + w) * 48) * 64 + lane) * 8;
#pragma unroll
    for (int f = 0; f < 48; ++f)
      wf[f] = *(const short8*)(base + (size_t)f * 64 * 8);
  }

  // bias (acc init), c state
  float4_ bia[4];
#pragma unroll
  for (int g = 0; g < 4; ++g)
    bia[g] = *(const float4_*)(bias + g * 256 + n0 + q * 4);
  float4_ c = *(const float4_*)(c0 + (size_t)bglob * 256 + n0 + q * 4);

  // x prefetch for t=0 (ktiles 8..11 of K)
  float4_ xr[8];
  {
    const float* xb = x + (size_t)bglob * 131072 + q * 8;
#pragma unroll
    for (int kx = 0; kx < 4; ++kx) {
      xr[kx * 2]     = *(const float4_*)(xb + kx * 32);
      xr[kx * 2 + 1] = *(const float4_*)(xb + kx * 32 + 4);
    }
  }

  const int fidx = grp * 4 + (lane & 3);    // lane-distributed flag poll
  int* const myflag = &flags[grp * 4 + s];

  float4_ hval;

  for (int t = 0; t < 1024; ++t) {
    const int p = t & 1;

    // convert prefetched x -> bf16 frags (work before the wait)
    short8 xf[4];
#pragma unroll
    for (int kx = 0; kx < 4; ++kx) {
      short8 v;
#pragma unroll
      for (int e = 0; e < 4; ++e) {
        v[e]     = (short)f2bf(xr[kx * 2][e]);
        v[e + 4] = (short)f2bf(xr[kx * 2 + 1][e]);
      }
      xf[kx] = v;
    }
    // prefetch next step's x (full step of latency cover)
    {
      int tn = (t < 1023) ? (t + 1) : 1023;
      const float* xb = x + (size_t)bglob * 131072 + (size_t)tn * 128 + q * 8;
#pragma unroll
      for (int kx = 0; kx < 4; ++kx) {
        xr[kx * 2]     = *(const float4_*)(xb + kx * 32);
        xr[kx * 2 + 1] = *(const float4_*)(xb + kx * 32 + 4);
      }
    }

    // ---- wait for all 16 producer waves of this group to post h_t ----
    {
      const int target = 4 * t;
      for (;;) {
        int f = __hip_atomic_load(&flags[fidx], __ATOMIC_RELAXED,
                                  __HIP_MEMORY_SCOPE_AGENT);
        if (__all(f >= target)) break;
        __builtin_amdgcn_s_sleep(1);
      }
      __builtin_amdgcn_fence(__ATOMIC_ACQUIRE, "agent");
    }

    // issue ALL h loads (own slice included) — latency hidden behind x MFMAs
    unsigned long long pl[16];
    {
      const unsigned long long* hb = (const unsigned long long*)(hbuf +
          ((size_t)((p * 16 + grp) * 16 + bl) * 256 + q * 8));
#pragma unroll
      for (int ss = 0; ss < 4; ++ss) {
        pl[ss * 4 + 0] = __hip_atomic_load(hb + ss * 16 + 0, __ATOMIC_RELAXED, __HIP_MEMORY_SCOPE_AGENT);
        pl[ss * 4 + 1] = __hip_atomic_load(hb + ss * 16 + 1, __ATOMIC_RELAXED, __HIP_MEMORY_SCOPE_AGENT);
        pl[ss * 4 + 2] = __hip_atomic_load(hb + ss * 16 + 8, __ATOMIC_RELAXED, __HIP_MEMORY_SCOPE_AGENT);
        pl[ss * 4 + 3] = __hip_atomic_load(hb + ss * 16 + 9, __ATOMIC_RELAXED, __HIP_MEMORY_SCOPE_AGENT);
      }
    }

    float4_ acc[4];
#pragma unroll
    for (int g = 0; g < 4; ++g) acc[g] = bia[g];

    // x contribution first (xf already in regs): ktiles 8..11
#pragma unroll
    for (int kx = 0; kx < 4; ++kx)
#pragma unroll
      for (int g = 0; g < 4; ++g)
        acc[g] = __builtin_amdgcn_mfma_f32_16x16x32_bf16(wf[g * 12 + 8 + kx], xf[kx], acc[g], 0, 0, 0);

    // h contribution: all 4 slices, fully static wf indices
#pragma unroll
    for (int ss = 0; ss < 4; ++ss) {
#pragma unroll
      for (int kt = 0; kt < 2; ++kt) {
        union { unsigned long long u[2]; short8 v; } uu;
        uu.u[0] = pl[ss * 4 + kt * 2 + 0];
        uu.u[1] = pl[ss * 4 + kt * 2 + 1];
#pragma unroll
        for (int g = 0; g < 4; ++g)
          acc[g] = __builtin_amdgcn_mfma_f32_16x16x32_bf16(wf[g * 12 + 2 * ss + kt], uu.v, acc[g], 0, 0, 0);
      }
    }

    // ---- gates / state update (fp32) ----
    unsigned short hp[4];
#pragma unroll
    for (int r = 0; r < 4; ++r) {
      float iv = sigm_(acc[0][r]);
      float fv = sigm_(acc[1][r]);
      float gv = tanh_(acc[2][r]);
      float ov = sigm_(acc[3][r]);
      float cv = fv * c[r] + iv * gv;
      c[r] = cv;
      float hv = ov * tanh_(cv);
      hval[r] = hv;
      hp[r] = f2bf(hv);
    }

    // write h_{t+1} (agent-scope 8B atomic store), then per-wave release flag
    {
      unsigned long long hu = (unsigned long long)hp[0]
                            | ((unsigned long long)hp[1] << 16)
                            | ((unsigned long long)hp[2] << 32)
                            | ((unsigned long long)hp[3] << 48);
      unsigned long long* dst = (unsigned long long*)(hbuf +
          ((size_t)(((1 - p) * 16 + grp) * 16 + bl) * 256 + n0 + q * 4));
      __hip_atomic_store(dst, hu, __ATOMIC_RELAXED, __HIP_MEMORY_SCOPE_AGENT);
    }
    if (lane == 0)
      __hip_atomic_fetch_add(myflag, 1, __ATOMIC_RELEASE,
                             __HIP_MEMORY_SCOPE_AGENT);
  }

  // final h (fp32) -> d_out [1,B,H]
  *(float4_*)(out + (size_t)bglob * 256 + n0 + q * 4) = hval;
}

extern "C" void kernel_launch(void* const* d_in, const int* in_sizes, int n_in,
                              void* d_out, int out_size, void* d_ws, size_t ws_size,
                              hipStream_t stream) {
  (void)in_sizes; (void)n_in; (void)out_size; (void)ws_size;
  const float* x    = (const float*)d_in[0];
  const float* h0   = (const float*)d_in[1];
  const float* c0   = (const float*)d_in[2];
  const float* w_ih = (const float*)d_in[3];
  const float* w_hh = (const float*)d_in[4];
  const float* b_ih = (const float*)d_in[5];
  const float* b_hh = (const float*)d_in[6];

  char* ws = (char*)d_ws;
  unsigned short* wpack = (unsigned short*)(ws + WPACK_OFF);
  unsigned short* hbuf  = (unsigned short*)(ws + HBUF_OFF);
  float*          bias  = (float*)(ws + BIAS_OFF);
  int*            flags = (int*)(ws + FLAGS_OFF);

  hipMemsetAsync(flags, 0, FLAGS_BYTES, stream);
  pack_w<<<192, 256, 0, stream>>>(w_ih, w_hh, wpack);
  init_hb<<<260, 256, 0, stream>>>(h0, b_ih, b_hh, hbuf, bias);
  lstm_main<<<64, 256, 0, stream>>>(x, c0, wpack, bias, hbuf, flags,
                                    (float*)d_out);
}

// Round 4
// 5743.590 us; speedup vs baseline: 2.0588x; 1.9913x over previous
//
#include <hip/hip_runtime.h>
#include <hip/hip_bf16.h>

typedef __attribute__((ext_vector_type(8))) short   short8;
typedef __attribute__((ext_vector_type(4))) float   float4_;

// ---------------- workspace layout (bytes) ----------------
#define WPACK_OFF   0
#define WPACK_BYTES 786432                    // 1024 rows x 384 k x 2B, A-frag packed
#define HBUF_OFF    786432
#define HBUF_BYTES  4194304                   // 32 slots x 16grp x 16b x 256k x bf16
#define BIAS_OFF    (HBUF_OFF + HBUF_BYTES)   // 4980736
#define BIAS_BYTES  4096
#define FLAGS_OFF   (BIAS_OFF + BIAS_BYTES)   // 4984832
#define FLAGS_BYTES 2048                      // 16 groups x 32-int padded counters

#define SLOT_ULL 16384                        // 16grp*16bl*64 ulls per step-slot
#define SENT_ULL 0xFFFFFFFFFFFFFFFFull        // bf16 NaN x4 — unreachable for finite h

__device__ __forceinline__ unsigned short f2bf(float f) {
  unsigned int u = __float_as_uint(f);
  u += 0x7fffu + ((u >> 16) & 1u);            // round-to-nearest-even
  return (unsigned short)(u >> 16);
}

// Pack W = [W_hh | W_ih] into MFMA A-fragment order, bf16.
// idx = (((s*4+w)*4+mt)*12+kt)*64+lane ; each thread writes one 16B frag.
__global__ void pack_w(const float* __restrict__ w_ih,
                       const float* __restrict__ w_hh,
                       unsigned short* __restrict__ wpack) {
  int idx = blockIdx.x * blockDim.x + threadIdx.x;
  if (idx >= 49152) return;
  int lane = idx & 63;
  int r1 = idx >> 6;
  int kt = r1 % 12;
  int r2 = r1 / 12;
  int mt = r2 & 3;          // gate (i,f,g,o)
  int r3 = r2 >> 2;
  int w  = r3 & 3;          // wave in block
  int s  = r3 >> 2;         // gate-slice (which block of the group)
  int row = mt * 256 + s * 64 + w * 16 + (lane & 15);
  int q = lane >> 4;
  short8 o;
#pragma unroll
  for (int j = 0; j < 8; ++j) {
    int kk = kt * 32 + q * 8 + j;             // 0..383
    float v = (kt < 8) ? w_hh[row * 256 + kk]
                       : w_ih[row * 128 + (kk - 256)];
    o[j] = (short)f2bf(v);
  }
  *(short8*)(wpack + (size_t)idx * 8) = o;
}

// Fill hbuf: slot 0 = bf16(h0), slots 1..31 = sentinel. Also bias = b_ih+b_hh.
__global__ void init_hb(const float* __restrict__ h0,
                        const float* __restrict__ b_ih,
                        const float* __restrict__ b_hh,
                        unsigned long long* __restrict__ hbuf,
                        float* __restrict__ bias) {
  int idx = blockIdx.x * blockDim.x + threadIdx.x;
  if (idx < 16384) {                           // slot 0: seed h0 (4 halves per ull)
    unsigned long long v = 0;
#pragma unroll
    for (int e = 0; e < 4; ++e)
      v |= (unsigned long long)f2bf(h0[idx * 4 + e]) << (16 * e);
    hbuf[idx] = v;
  } else if (idx < 524288) {                   // slots 1..31: sentinel
    hbuf[idx] = SENT_ULL;
  } else if (idx < 525312) {
    int j = idx - 524288;
    bias[j] = b_ih[j] + b_hh[j];
  }
}

__device__ __forceinline__ float sigm_(float v) {
  return 1.f / (1.f + __expf(-v));
}
__device__ __forceinline__ float tanh_(float v) {
  return 1.f - 2.f / (__expf(2.f * v) + 1.f);  // robust at +-inf
}

__global__ __launch_bounds__(256, 1) void lstm_main(
    const float* __restrict__ x, const float* __restrict__ c0,
    const unsigned short* __restrict__ wpack, const float* __restrict__ bias,
    unsigned long long* hbuf, int* flags, float* __restrict__ out) {

  const int tid  = threadIdx.x;
  const int w    = tid >> 6;       // wave 0..3
  const int lane = tid & 63;
  const int q    = lane >> 4;
  const int bl   = lane & 15;

  // XCD-affinity swizzle: the 4 blocks of a group share blockIdx%8 (same XCD).
  int id  = blockIdx.x;
  int xcd = id & 7;
  int j3  = id >> 3;
  int s   = j3 & 3;                         // gate-slice 0..3
  int grp = (j3 >> 2) * 8 + xcd;            // batch group 0..15

  const int n0    = s * 64 + w * 16;        // wave's first h-element
  const int bglob = grp * 16 + bl;

  // ---- W fragments in VGPRs: 4 gates x 12 ktiles (static idx, loop-invariant,
  //      no fences in the hot loop -> hoistable/resident) ----
  short8 wf[48];
  {
    const unsigned short* base =
        wpack + ((size_t)((s * 4 + w) * 48) * 64 + lane) * 8;
#pragma unroll
    for (int f = 0; f < 48; ++f)
      wf[f] = *(const short8*)(base + (size_t)f * 64 * 8);
  }

  // bias (acc init), c state
  float4_ bia[4];
#pragma unroll
  for (int g = 0; g < 4; ++g)
    bia[g] = *(const float4_*)(bias + g * 256 + n0 + q * 4);
  float4_ c = *(const float4_*)(c0 + (size_t)bglob * 256 + n0 + q * 4);

  // x prefetch for t=0 (ktiles 8..11 of K)
  float4_ xr[8];
  {
    const float* xb = x + (size_t)bglob * 131072 + q * 8;
#pragma unroll
    for (int kx = 0; kx < 4; ++kx) {
      xr[kx * 2]     = *(const float4_*)(xb + kx * 32);
      xr[kx * 2 + 1] = *(const float4_*)(xb + kx * 32 + 4);
    }
  }

  // per-(grp,bl) ull base inside one step-slot; step slot adds (t&31)*SLOT_ULL
  const size_t hb_base = ((size_t)grp * 16 + bl) * 64;
  const size_t my_off  = hb_base + (n0 >> 2) + q;      // this wave's output chunk
  int* const cnt = &flags[grp * 32];

  float4_ hval;

#pragma unroll 1
  for (int t = 0; t < 1024; ++t) {
    // convert prefetched x -> bf16 frags (work done before/while h arrives)
    short8 xf[4];
#pragma unroll
    for (int kx = 0; kx < 4; ++kx) {
      short8 v;
#pragma unroll
      for (int e = 0; e < 4; ++e) {
        v[e]     = (short)f2bf(xr[kx * 2][e]);
        v[e + 4] = (short)f2bf(xr[kx * 2 + 1][e]);
      }
      xf[kx] = v;
    }
    // prefetch next step's x (full step of latency cover)
    {
      int tn = (t < 1023) ? (t + 1) : 1023;
      const float* xb = x + (size_t)bglob * 131072 + (size_t)tn * 128 + q * 8;
#pragma unroll
      for (int kx = 0; kx < 4; ++kx) {
        xr[kx * 2]     = *(const float4_*)(xb + kx * 32);
        xr[kx * 2 + 1] = *(const float4_*)(xb + kx * 32 + 4);
      }
    }

    // ---- poll h_t directly (data-embedded sync; the poll IS the load) ----
    unsigned long long pl[16];
    {
      unsigned long long* hb = hbuf + (size_t)(t & 31) * SLOT_ULL + hb_base + q * 2;
      for (;;) {
#pragma unroll
        for (int ss = 0; ss < 4; ++ss) {
          pl[ss * 4 + 0] = __hip_atomic_load(hb + ss * 16 + 0, __ATOMIC_RELAXED, __HIP_MEMORY_SCOPE_AGENT);
          pl[ss * 4 + 1] = __hip_atomic_load(hb + ss * 16 + 1, __ATOMIC_RELAXED, __HIP_MEMORY_SCOPE_AGENT);
          pl[ss * 4 + 2] = __hip_atomic_load(hb + ss * 16 + 8, __ATOMIC_RELAXED, __HIP_MEMORY_SCOPE_AGENT);
          pl[ss * 4 + 3] = __hip_atomic_load(hb + ss * 16 + 9, __ATOMIC_RELAXED, __HIP_MEMORY_SCOPE_AGENT);
        }
        bool ok = true;
#pragma unroll
        for (int i = 0; i < 16; ++i)
          ok &= ((unsigned)(pl[i] & 0xFFFFull) != 0xFFFFu);
        if (__all(ok)) break;
        __builtin_amdgcn_s_sleep(1);
      }
    }

    float4_ acc[4];
#pragma unroll
    for (int g = 0; g < 4; ++g) acc[g] = bia[g];

    // x contribution (regs ready): ktiles 8..11
#pragma unroll
    for (int kx = 0; kx < 4; ++kx)
#pragma unroll
      for (int g = 0; g < 4; ++g)
        acc[g] = __builtin_amdgcn_mfma_f32_16x16x32_bf16(wf[g * 12 + 8 + kx], xf[kx], acc[g], 0, 0, 0);

    // h contribution: all 4 slices, fully static wf indices
#pragma unroll
    for (int ss = 0; ss < 4; ++ss) {
#pragma unroll
      for (int kt = 0; kt < 2; ++kt) {
        union { unsigned long long u[2]; short8 v; } uu;
        uu.u[0] = pl[ss * 4 + kt * 2 + 0];
        uu.u[1] = pl[ss * 4 + kt * 2 + 1];
#pragma unroll
        for (int g = 0; g < 4; ++g)
          acc[g] = __builtin_amdgcn_mfma_f32_16x16x32_bf16(wf[g * 12 + 2 * ss + kt], uu.v, acc[g], 0, 0, 0);
      }
    }

    // ---- gates / state update (fp32) ----
    unsigned short hp[4];
#pragma unroll
    for (int r = 0; r < 4; ++r) {
      float iv = sigm_(acc[0][r]);
      float fv = sigm_(acc[1][r]);
      float gv = tanh_(acc[2][r]);
      float ov = sigm_(acc[3][r]);
      float cv = fv * c[r] + iv * gv;
      c[r] = cv;
      float hv = ov * tanh_(cv);
      hval[r] = hv;
      hp[r] = f2bf(hv);
    }

    // write h_{t+1} chunk (single atomic 8B store -> slot (t+1)&31)
    {
      unsigned long long hu = (unsigned long long)hp[0]
                            | ((unsigned long long)hp[1] << 16)
                            | ((unsigned long long)hp[2] << 32)
                            | ((unsigned long long)hp[3] << 48);
      unsigned long long* dst = hbuf + (size_t)((t + 1) & 31) * SLOT_ULL + my_off;
      __hip_atomic_store(dst, hu, __ATOMIC_RELAXED, __HIP_MEMORY_SCOPE_AGENT);
    }

    // ---- every 8 steps: reset old slots + group barrier (amortized) ----
    if ((t & 7) == 7 && t != 1023) {
      const int k = t >> 3;                 // t == 8k+7
      // re-sentinel this wave's own chunks for steps m in [8k-15, 8k-8]
#pragma unroll
      for (int j = 0; j < 8; ++j) {
        int m = 8 * k - 15 + j;
        if (m >= 0) {
          unsigned long long* rp = hbuf + (size_t)(m & 31) * SLOT_ULL + my_off;
          __hip_atomic_store(rp, SENT_ULL, __ATOMIC_RELAXED, __HIP_MEMORY_SCOPE_AGENT);
        }
      }
      if (lane == 0)
        __hip_atomic_fetch_add(cnt, 1, __ATOMIC_RELEASE, __HIP_MEMORY_SCOPE_AGENT);
      const int target = 16 * (k + 1);
      for (;;) {
        int v = __hip_atomic_load(cnt, __ATOMIC_RELAXED, __HIP_MEMORY_SCOPE_AGENT);
        if (v >= target) break;
        __builtin_amdgcn_s_sleep(1);
      }
      __builtin_amdgcn_fence(__ATOMIC_ACQUIRE, "agent");
    }
  }

  // final h (fp32) -> d_out [1,B,H]
  *(float4_*)(out + (size_t)bglob * 256 + n0 + q * 4) = hval;
}

extern "C" void kernel_launch(void* const* d_in, const int* in_sizes, int n_in,
                              void* d_out, int out_size, void* d_ws, size_t ws_size,
                              hipStream_t stream) {
  (void)in_sizes; (void)n_in; (void)out_size; (void)ws_size;
  const float* x    = (const float*)d_in[0];
  const float* h0   = (const float*)d_in[1];
  const float* c0   = (const float*)d_in[2];
  const float* w_ih = (const float*)d_in[3];
  const float* w_hh = (const float*)d_in[4];
  const float* b_ih = (const float*)d_in[5];
  const float* b_hh = (const float*)d_in[6];

  char* ws = (char*)d_ws;
  unsigned short*     wpack = (unsigned short*)(ws + WPACK_OFF);
  unsigned long long* hbuf  = (unsigned long long*)(ws + HBUF_OFF);
  float*              bias  = (float*)(ws + BIAS_OFF);
  int*                flags = (int*)(ws + FLAGS_OFF);

  hipMemsetAsync(flags, 0, FLAGS_BYTES, stream);
  pack_w<<<192, 256, 0, stream>>>(w_ih, w_hh, wpack);
  init_hb<<<2053, 256, 0, stream>>>(h0, b_ih, b_hh, hbuf, bias);
  lstm_main<<<64, 256, 0, stream>>>(x, c0, wpack, bias, hbuf, flags,
                                    (float*)d_out);
}